// Round 1
// baseline (912.617 us; speedup 1.0000x reference)
//
#include <hip/hip_runtime.h>

#define CH 128

// ---------------------------------------------------------------- init out=0
__global__ void k_init(float4* __restrict__ out, int n4) {
  int i = blockIdx.x * blockDim.x + threadIdx.x;
  int stride = gridDim.x * blockDim.x;
  float4 z = make_float4(0.f, 0.f, 0.f, 0.f);
  for (; i < n4; i += stride) out[i] = z;
}

// ------------------------------------------------- scatter: out[r] += v*x[c]
// one (edge, channel) pair per loop iteration; a wave's 64 lanes cover 64
// consecutive channels of one edge -> coalesced 256B x-load + 256B atomics.
__global__ void k_scatter(const float* __restrict__ x,
                          const int* __restrict__ rows,
                          const int* __restrict__ cols,
                          const float* __restrict__ vals,
                          float* __restrict__ out, int nEdges) {
  long long total = (long long)nEdges * CH;
  long long stride = (long long)gridDim.x * blockDim.x;
  for (long long i = (long long)blockIdx.x * blockDim.x + threadIdx.x;
       i < total; i += stride) {
    int e = (int)(i >> 7);
    int c = (int)(i & 127);
    int r = rows[e];
    int cl = cols[e];
    float v = vals[e];
    unsafeAtomicAdd(out + (((long long)r) << 7) + c,
                    v * x[(((long long)cl) << 7) + c]);
  }
}

// --------------------------------------- in-place projection: out = agg@W^T+b
// W^T staged in LDS (64KB) once per block; 2 rows per block-iteration.
// sWt read pattern: lanes o consecutive -> conflict-free; sRow[c] broadcast.
__global__ __launch_bounds__(256) void k_project(float* __restrict__ out,
                                                 const float* __restrict__ W,
                                                 const float* __restrict__ bias,
                                                 int nNodes) {
  __shared__ float sWt[CH * CH];   // sWt[c*128+o] = W[o*128+c]
  __shared__ float sRow[2][CH];
  for (int idx = threadIdx.x; idx < CH * CH; idx += 256) {
    int o = idx >> 7, c = idx & 127;
    sWt[c * CH + o] = W[idx];
  }
  int rl = threadIdx.x >> 7;   // 0 or 1
  int o  = threadIdx.x & 127;
  float bv = bias[o];
  __syncthreads();
  for (int r0 = blockIdx.x * 2; r0 < nNodes; r0 += gridDim.x * 2) {
    int r = r0 + rl;
    float rv = (r < nNodes) ? out[(((long long)r) << 7) + o] : 0.f;
    sRow[rl][o] = rv;
    __syncthreads();
    float acc = bv;
#pragma unroll
    for (int c = 0; c < CH; ++c)
      acc = fmaf(sRow[rl][c], sWt[c * CH + o], acc);
    if (r < nNodes) out[(((long long)r) << 7) + o] = acc;
    __syncthreads();
  }
}

extern "C" void kernel_launch(void* const* d_in, const int* in_sizes, int n_in,
                              void* d_out, int out_size, void* d_ws, size_t ws_size,
                              hipStream_t stream) {
  const float* x    = (const float*)d_in[0];
  const int*   rows = (const int*)d_in[1];
  const int*   cols = (const int*)d_in[2];
  const float* vals = (const float*)d_in[3];
  const float* W    = (const float*)d_in[4];
  const float* b    = (const float*)d_in[5];
  float* out = (float*)d_out;

  int nEdges = in_sizes[1];
  int nNodes = in_sizes[0] / CH;
  int n4 = out_size / 4;

  hipLaunchKernelGGL(k_init, dim3(2048), dim3(256), 0, stream, (float4*)out, n4);
  hipLaunchKernelGGL(k_scatter, dim3(4096), dim3(256), 0, stream,
                     x, rows, cols, vals, out, nEdges);
  hipLaunchKernelGGL(k_project, dim3(2048), dim3(256), 0, stream,
                     out, W, b, nNodes);
}

// Round 2
// 401.192 us; speedup vs baseline: 2.2748x; 2.2748x over previous
//
#include <hip/hip_runtime.h>

#define CH 128
#define SCAN_CHUNK 1024

// ============================ fallback path (R1) ============================
__global__ void k_init(float4* __restrict__ out, int n4) {
  int i = blockIdx.x * blockDim.x + threadIdx.x;
  int stride = gridDim.x * blockDim.x;
  float4 z = make_float4(0.f, 0.f, 0.f, 0.f);
  for (; i < n4; i += stride) out[i] = z;
}

__global__ void k_scatter(const float* __restrict__ x,
                          const int* __restrict__ rows,
                          const int* __restrict__ cols,
                          const float* __restrict__ vals,
                          float* __restrict__ out, int nEdges) {
  long long total = (long long)nEdges * CH;
  long long stride = (long long)gridDim.x * blockDim.x;
  for (long long i = (long long)blockIdx.x * blockDim.x + threadIdx.x;
       i < total; i += stride) {
    int e = (int)(i >> 7);
    int c = (int)(i & 127);
    unsafeAtomicAdd(out + (((long long)rows[e]) << 7) + c,
                    vals[e] * x[(((long long)cols[e]) << 7) + c]);
  }
}

// ============================ CSR build =====================================
__global__ void k_hist(const int* __restrict__ rows, int* __restrict__ cnt,
                       int nE) {
  int i = blockIdx.x * blockDim.x + threadIdx.x;
  int stride = gridDim.x * blockDim.x;
  for (; i < nE; i += stride) atomicAdd(&cnt[rows[i]], 1);
}

// block-local exclusive scan of 1024 elements, emits block sums
__global__ __launch_bounds__(256) void k_scan1(const int* __restrict__ cnt,
                                               int* __restrict__ rowPtr,
                                               int* __restrict__ blockSum,
                                               int n) {
  __shared__ int sSum[256];
  int b = blockIdx.x, t = threadIdx.x;
  int base = b * SCAN_CHUNK + t * 4;
  int v[4];
  int s = 0;
#pragma unroll
  for (int k = 0; k < 4; ++k) {
    int idx = base + k;
    v[k] = (idx < n) ? cnt[idx] : 0;
    s += v[k];
  }
  sSum[t] = s;
  __syncthreads();
  for (int off = 1; off < 256; off <<= 1) {
    int add = (t >= off) ? sSum[t - off] : 0;
    __syncthreads();
    sSum[t] += add;
    __syncthreads();
  }
  int run = sSum[t] - s;  // exclusive prefix of this thread within block
  if (t == 255) blockSum[b] = sSum[255];
#pragma unroll
  for (int k = 0; k < 4; ++k) {
    int idx = base + k;
    if (idx < n) rowPtr[idx] = run;
    run += v[k];
  }
}

// scan of <=256 block sums (one block), also writes rowPtr[N] = total
__global__ __launch_bounds__(256) void k_scan2(const int* __restrict__ blockSum,
                                               int* __restrict__ blockOff,
                                               int* __restrict__ rowPtrEnd,
                                               int nb) {
  __shared__ int s[256];
  int t = threadIdx.x;
  int v = (t < nb) ? blockSum[t] : 0;
  s[t] = v;
  __syncthreads();
  for (int off = 1; off < 256; off <<= 1) {
    int add = (t >= off) ? s[t - off] : 0;
    __syncthreads();
    s[t] += add;
    __syncthreads();
  }
  if (t < nb) blockOff[t] = s[t] - v;
  if (t == 255) *rowPtrEnd = s[255];
}

__global__ __launch_bounds__(256) void k_scan3(int* __restrict__ rowPtr,
                                               int* __restrict__ cursor,
                                               const int* __restrict__ blockOff,
                                               int n) {
  int b = blockIdx.x;
  int off = blockOff[b];
  int i = b * SCAN_CHUNK + threadIdx.x;
#pragma unroll
  for (int k = 0; k < 4; ++k, i += 256) {
    if (i < n) {
      int vv = rowPtr[i] + off;
      rowPtr[i] = vv;
      cursor[i] = vv;
    }
  }
}

__global__ void k_fill(const int* __restrict__ rows,
                       const int* __restrict__ cols,
                       const float* __restrict__ vals,
                       int* __restrict__ cursor, int* __restrict__ ecols,
                       float* __restrict__ evals, int nE) {
  int i = blockIdx.x * blockDim.x + threadIdx.x;
  int stride = gridDim.x * blockDim.x;
  for (; i < nE; i += stride) {
    int p = atomicAdd(&cursor[rows[i]], 1);
    ecols[p] = cols[i];
    evals[p] = vals[i];
  }
}

// ==================== aggregate: one wave per row ===========================
// lane owns channels (2*lane, 2*lane+1); edges preloaded 64-wide, broadcast
// via shfl; x-row gather is one coalesced 512B float2 load per edge.
__global__ __launch_bounds__(256) void k_aggregate(
    const float* __restrict__ x, const int* __restrict__ rowPtr,
    const int* __restrict__ ecols, const float* __restrict__ evals,
    float* __restrict__ out, int nNodes) {
  int wave = blockIdx.x * 4 + (threadIdx.x >> 6);
  int lane = threadIdx.x & 63;
  if (wave >= nNodes) return;
  int n0 = rowPtr[wave], n1 = rowPtr[wave + 1];
  float2 acc = make_float2(0.f, 0.f);
  for (int base = n0; base < n1; base += 64) {
    int m = n1 - base;
    if (m > 64) m = 64;
    int col = 0;
    float v = 0.f;
    if (lane < m) {
      col = ecols[base + lane];
      v = evals[base + lane];
    }
    for (int j = 0; j < m; ++j) {
      int cj = __shfl(col, j);
      float vj = __shfl(v, j);
      const float2 xv = *reinterpret_cast<const float2*>(
          x + (((long long)cj) << 7) + (lane << 1));
      acc.x = fmaf(vj, xv.x, acc.x);
      acc.y = fmaf(vj, xv.y, acc.y);
    }
  }
  *reinterpret_cast<float2*>(out + (((long long)wave) << 7) + (lane << 1)) = acc;
}

// ==================== projection: out = agg @ W^T + b (in place) ============
// 64 rows x 128 outs per block; thread (og,rg) owns 8 rows x 4 outs.
// Per c: 1x b128 W-read + 2x b128 A-reads for 32 FMAs.
#define PRJ_ROWS 64
__global__ __launch_bounds__(256) void k_project(float* __restrict__ out,
                                                 const float* __restrict__ W,
                                                 const float* __restrict__ bias,
                                                 int nNodes) {
  __shared__ float sWt[CH * CH];  // [c][o], xor-swizzled
  __shared__ float sA[8 * 68];    // [kc][r], padded to 68
  int tid = threadIdx.x;
  int og = tid & 31, rg = tid >> 5;
  for (int idx = tid; idx < CH * CH; idx += 256) {
    int o = idx >> 7, c = idx & 127;
    sWt[(c * CH + o) ^ ((c & 31) << 2)] = W[idx];
  }
  int row0 = blockIdx.x * PRJ_ROWS;
  float acc[8][4];
#pragma unroll
  for (int i = 0; i < 8; ++i)
#pragma unroll
    for (int j = 0; j < 4; ++j) acc[i][j] = 0.f;
  int sr = tid >> 2;         // 0..63 (row within tile)
  int skc = (tid & 3) << 1;  // 0,2,4,6
  __syncthreads();
  for (int kk = 0; kk < CH; kk += 8) {
    float2 av = make_float2(0.f, 0.f);
    int grow = row0 + sr;
    if (grow < nNodes)
      av = *reinterpret_cast<const float2*>(out + (((long long)grow) << 7) +
                                            kk + skc);
    sA[skc * 68 + sr] = av.x;
    sA[(skc + 1) * 68 + sr] = av.y;
    __syncthreads();
#pragma unroll
    for (int kc = 0; kc < 8; ++kc) {
      int c = kk + kc;
      const float4 w4 = *reinterpret_cast<const float4*>(
          &sWt[(c * CH + (og << 2)) ^ ((c & 31) << 2)]);
      const float4 a0 =
          *reinterpret_cast<const float4*>(&sA[kc * 68 + (rg << 3)]);
      const float4 a1 =
          *reinterpret_cast<const float4*>(&sA[kc * 68 + (rg << 3) + 4]);
      acc[0][0] = fmaf(a0.x, w4.x, acc[0][0]);
      acc[0][1] = fmaf(a0.x, w4.y, acc[0][1]);
      acc[0][2] = fmaf(a0.x, w4.z, acc[0][2]);
      acc[0][3] = fmaf(a0.x, w4.w, acc[0][3]);
      acc[1][0] = fmaf(a0.y, w4.x, acc[1][0]);
      acc[1][1] = fmaf(a0.y, w4.y, acc[1][1]);
      acc[1][2] = fmaf(a0.y, w4.z, acc[1][2]);
      acc[1][3] = fmaf(a0.y, w4.w, acc[1][3]);
      acc[2][0] = fmaf(a0.z, w4.x, acc[2][0]);
      acc[2][1] = fmaf(a0.z, w4.y, acc[2][1]);
      acc[2][2] = fmaf(a0.z, w4.z, acc[2][2]);
      acc[2][3] = fmaf(a0.z, w4.w, acc[2][3]);
      acc[3][0] = fmaf(a0.w, w4.x, acc[3][0]);
      acc[3][1] = fmaf(a0.w, w4.y, acc[3][1]);
      acc[3][2] = fmaf(a0.w, w4.z, acc[3][2]);
      acc[3][3] = fmaf(a0.w, w4.w, acc[3][3]);
      acc[4][0] = fmaf(a1.x, w4.x, acc[4][0]);
      acc[4][1] = fmaf(a1.x, w4.y, acc[4][1]);
      acc[4][2] = fmaf(a1.x, w4.z, acc[4][2]);
      acc[4][3] = fmaf(a1.x, w4.w, acc[4][3]);
      acc[5][0] = fmaf(a1.y, w4.x, acc[5][0]);
      acc[5][1] = fmaf(a1.y, w4.y, acc[5][1]);
      acc[5][2] = fmaf(a1.y, w4.z, acc[5][2]);
      acc[5][3] = fmaf(a1.y, w4.w, acc[5][3]);
      acc[6][0] = fmaf(a1.z, w4.x, acc[6][0]);
      acc[6][1] = fmaf(a1.z, w4.y, acc[6][1]);
      acc[6][2] = fmaf(a1.z, w4.z, acc[6][2]);
      acc[6][3] = fmaf(a1.z, w4.w, acc[6][3]);
      acc[7][0] = fmaf(a1.w, w4.x, acc[7][0]);
      acc[7][1] = fmaf(a1.w, w4.y, acc[7][1]);
      acc[7][2] = fmaf(a1.w, w4.z, acc[7][2]);
      acc[7][3] = fmaf(a1.w, w4.w, acc[7][3]);
    }
    __syncthreads();
  }
  int o0 = og << 2;
  const float4 bv = *reinterpret_cast<const float4*>(&bias[o0]);
#pragma unroll
  for (int i = 0; i < 8; ++i) {
    int r = row0 + (rg << 3) + i;
    if (r < nNodes) {
      float4 res = make_float4(acc[i][0] + bv.x, acc[i][1] + bv.y,
                               acc[i][2] + bv.z, acc[i][3] + bv.w);
      *reinterpret_cast<float4*>(out + (((long long)r) << 7) + o0) = res;
    }
  }
}

extern "C" void kernel_launch(void* const* d_in, const int* in_sizes, int n_in,
                              void* d_out, int out_size, void* d_ws,
                              size_t ws_size, hipStream_t stream) {
  const float* x = (const float*)d_in[0];
  const int* rows = (const int*)d_in[1];
  const int* cols = (const int*)d_in[2];
  const float* vals = (const float*)d_in[3];
  const float* W = (const float*)d_in[4];
  const float* b = (const float*)d_in[5];
  float* out = (float*)d_out;

  int nEdges = in_sizes[1];
  int nNodes = in_sizes[0] / CH;
  int nPrjBlocks = (nNodes + PRJ_ROWS - 1) / PRJ_ROWS;
  int NB = (nNodes + SCAN_CHUNK - 1) / SCAN_CHUNK;

  // ws layout (ints): rowPtr[N+1] | cnt[N] | cursor[N] | bsum[256] | boff[256]
  //                   | ecols[E] | evals[E]
  size_t needInts = (size_t)(3 * nNodes + 1 + 512) + 2 * (size_t)nEdges;
  size_t needBytes = needInts * 4;

  if (ws_size < needBytes || NB > 256) {
    // fallback: atomic scatter path
    hipLaunchKernelGGL(k_init, dim3(2048), dim3(256), 0, stream, (float4*)out,
                       out_size / 4);
    hipLaunchKernelGGL(k_scatter, dim3(4096), dim3(256), 0, stream, x, rows,
                       cols, vals, out, nEdges);
    hipLaunchKernelGGL(k_project, dim3(nPrjBlocks), dim3(256), 0, stream, out,
                       W, b, nNodes);
    return;
  }

  int* wsI = (int*)d_ws;
  int* rowPtr = wsI;
  int* cnt = rowPtr + (nNodes + 1);
  int* cursor = cnt + nNodes;
  int* bsum = cursor + nNodes;
  int* boff = bsum + 256;
  int* ecols = boff + 256;
  float* evals = (float*)(ecols + nEdges);

  hipMemsetAsync(cnt, 0, (size_t)nNodes * 4, stream);
  hipLaunchKernelGGL(k_hist, dim3(2048), dim3(256), 0, stream, rows, cnt,
                     nEdges);
  hipLaunchKernelGGL(k_scan1, dim3(NB), dim3(256), 0, stream, cnt, rowPtr,
                     bsum, nNodes);
  hipLaunchKernelGGL(k_scan2, dim3(1), dim3(256), 0, stream, bsum, boff,
                     rowPtr + nNodes, NB);
  hipLaunchKernelGGL(k_scan3, dim3(NB), dim3(256), 0, stream, rowPtr, cursor,
                     boff, nNodes);
  hipLaunchKernelGGL(k_fill, dim3(2048), dim3(256), 0, stream, rows, cols,
                     vals, cursor, ecols, evals, nEdges);
  hipLaunchKernelGGL(k_aggregate, dim3((nNodes + 3) / 4), dim3(256), 0, stream,
                     x, rowPtr, ecols, evals, out, nNodes);
  hipLaunchKernelGGL(k_project, dim3(nPrjBlocks), dim3(256), 0, stream, out, W,
                     b, nNodes);
}

// Round 3
// 383.760 us; speedup vs baseline: 2.3781x; 1.0454x over previous
//
#include <hip/hip_runtime.h>

#define CH 128
#define SCAN_CHUNK 1024

// ============================ fallback path (R1) ============================
__global__ void k_init(float4* __restrict__ out, int n4) {
  int i = blockIdx.x * blockDim.x + threadIdx.x;
  int stride = gridDim.x * blockDim.x;
  float4 z = make_float4(0.f, 0.f, 0.f, 0.f);
  for (; i < n4; i += stride) out[i] = z;
}

__global__ void k_scatter(const float* __restrict__ x,
                          const int* __restrict__ rows,
                          const int* __restrict__ cols,
                          const float* __restrict__ vals,
                          float* __restrict__ out, int nEdges) {
  long long total = (long long)nEdges * CH;
  long long stride = (long long)gridDim.x * blockDim.x;
  for (long long i = (long long)blockIdx.x * blockDim.x + threadIdx.x;
       i < total; i += stride) {
    int e = (int)(i >> 7);
    int c = (int)(i & 127);
    unsafeAtomicAdd(out + (((long long)rows[e]) << 7) + c,
                    vals[e] * x[(((long long)cols[e]) << 7) + c]);
  }
}

// ============================ CSR build =====================================
__global__ void k_hist(const int* __restrict__ rows, int* __restrict__ cnt,
                       int nE) {
  int i = blockIdx.x * blockDim.x + threadIdx.x;
  int stride = gridDim.x * blockDim.x;
  for (; i < nE; i += stride) atomicAdd(&cnt[rows[i]], 1);
}

__global__ __launch_bounds__(256) void k_scan1(const int* __restrict__ cnt,
                                               int* __restrict__ rowPtr,
                                               int* __restrict__ blockSum,
                                               int n) {
  __shared__ int sSum[256];
  int b = blockIdx.x, t = threadIdx.x;
  int base = b * SCAN_CHUNK + t * 4;
  int v[4];
  int s = 0;
#pragma unroll
  for (int k = 0; k < 4; ++k) {
    int idx = base + k;
    v[k] = (idx < n) ? cnt[idx] : 0;
    s += v[k];
  }
  sSum[t] = s;
  __syncthreads();
  for (int off = 1; off < 256; off <<= 1) {
    int add = (t >= off) ? sSum[t - off] : 0;
    __syncthreads();
    sSum[t] += add;
    __syncthreads();
  }
  int run = sSum[t] - s;
  if (t == 255) blockSum[b] = sSum[255];
#pragma unroll
  for (int k = 0; k < 4; ++k) {
    int idx = base + k;
    if (idx < n) rowPtr[idx] = run;
    run += v[k];
  }
}

__global__ __launch_bounds__(256) void k_scan2(const int* __restrict__ blockSum,
                                               int* __restrict__ blockOff,
                                               int* __restrict__ rowPtrEnd,
                                               int nb) {
  __shared__ int s[256];
  int t = threadIdx.x;
  int v = (t < nb) ? blockSum[t] : 0;
  s[t] = v;
  __syncthreads();
  for (int off = 1; off < 256; off <<= 1) {
    int add = (t >= off) ? s[t - off] : 0;
    __syncthreads();
    s[t] += add;
    __syncthreads();
  }
  if (t < nb) blockOff[t] = s[t] - v;
  if (t == 255) *rowPtrEnd = s[255];
}

__global__ __launch_bounds__(256) void k_scan3(int* __restrict__ rowPtr,
                                               int* __restrict__ cursor,
                                               const int* __restrict__ blockOff,
                                               int n) {
  int b = blockIdx.x;
  int off = blockOff[b];
  int i = b * SCAN_CHUNK + threadIdx.x;
#pragma unroll
  for (int k = 0; k < 4; ++k, i += 256) {
    if (i < n) {
      int vv = rowPtr[i] + off;
      rowPtr[i] = vv;
      cursor[i] = vv;
    }
  }
}

// packed scatter: one 8B write per edge instead of two 4B writes
__global__ void k_fill(const int* __restrict__ rows,
                       const int* __restrict__ cols,
                       const float* __restrict__ vals,
                       int* __restrict__ cursor, int2* __restrict__ ecv,
                       int nE) {
  int i = blockIdx.x * blockDim.x + threadIdx.x;
  int stride = gridDim.x * blockDim.x;
  for (; i < nE; i += stride) {
    int p = atomicAdd(&cursor[rows[i]], 1);
    ecv[p] = make_int2(cols[i], __float_as_int(vals[i]));
  }
}

// ==================== aggregate: one wave per row ===========================
// Wave split into two 32-lane halves; half h processes edge (j+h) of each
// 64-edge chunk with a float4 (16B/lane) x-row load; halves combined via
// shfl_xor(32) at the end. Lanes >= m hold col=0,v=0 so no tail guard needed.
__global__ __launch_bounds__(256) void k_aggregate(
    const float* __restrict__ x, const int* __restrict__ rowPtr,
    const int2* __restrict__ ecv, float* __restrict__ out, int nNodes) {
  int wave = blockIdx.x * 4 + (threadIdx.x >> 6);
  int lane = threadIdx.x & 63;
  if (wave >= nNodes) return;
  int n0 = rowPtr[wave], n1 = rowPtr[wave + 1];
  int half = lane >> 5;
  int c4 = (lane & 31) << 2;  // channel base 0..124
  float4 acc = make_float4(0.f, 0.f, 0.f, 0.f);
  for (int base = n0; base < n1; base += 64) {
    int m = n1 - base;
    if (m > 64) m = 64;
    int col = 0;
    float v = 0.f;
    if (lane < m) {
      int2 e = ecv[base + lane];
      col = e.x;
      v = __int_as_float(e.y);
    }
    for (int j = 0; j < m; j += 2) {
      int idx = j + half;
      int cj = __shfl(col, idx);
      float vj = __shfl(v, idx);
      const float4 xv =
          *reinterpret_cast<const float4*>(x + (((long long)cj) << 7) + c4);
      acc.x = fmaf(vj, xv.x, acc.x);
      acc.y = fmaf(vj, xv.y, acc.y);
      acc.z = fmaf(vj, xv.z, acc.z);
      acc.w = fmaf(vj, xv.w, acc.w);
    }
  }
  acc.x += __shfl_xor(acc.x, 32);
  acc.y += __shfl_xor(acc.y, 32);
  acc.z += __shfl_xor(acc.z, 32);
  acc.w += __shfl_xor(acc.w, 32);
  if (half == 0)
    *reinterpret_cast<float4*>(out + (((long long)wave) << 7) + c4) = acc;
}

// ==================== projection: out = agg @ W^T + b (in place) ============
#define PRJ_ROWS 64
__global__ __launch_bounds__(256) void k_project(float* __restrict__ out,
                                                 const float* __restrict__ W,
                                                 const float* __restrict__ bias,
                                                 int nNodes) {
  __shared__ float sWt[CH * CH];  // [c][o], xor-swizzled
  __shared__ float sA[8 * 68];    // [kc][r], padded
  int tid = threadIdx.x;
  int og = tid & 31, rg = tid >> 5;
  for (int idx = tid; idx < CH * CH; idx += 256) {
    int o = idx >> 7, c = idx & 127;
    sWt[(c * CH + o) ^ ((c & 31) << 2)] = W[idx];
  }
  int row0 = blockIdx.x * PRJ_ROWS;
  float acc[8][4];
#pragma unroll
  for (int i = 0; i < 8; ++i)
#pragma unroll
    for (int j = 0; j < 4; ++j) acc[i][j] = 0.f;
  int sr = tid >> 2;
  int skc = (tid & 3) << 1;
  __syncthreads();
  for (int kk = 0; kk < CH; kk += 8) {
    float2 av = make_float2(0.f, 0.f);
    int grow = row0 + sr;
    if (grow < nNodes)
      av = *reinterpret_cast<const float2*>(out + (((long long)grow) << 7) +
                                            kk + skc);
    sA[skc * 68 + sr] = av.x;
    sA[(skc + 1) * 68 + sr] = av.y;
    __syncthreads();
#pragma unroll
    for (int kc = 0; kc < 8; ++kc) {
      int c = kk + kc;
      const float4 w4 = *reinterpret_cast<const float4*>(
          &sWt[(c * CH + (og << 2)) ^ ((c & 31) << 2)]);
      const float4 a0 =
          *reinterpret_cast<const float4*>(&sA[kc * 68 + (rg << 3)]);
      const float4 a1 =
          *reinterpret_cast<const float4*>(&sA[kc * 68 + (rg << 3) + 4]);
      acc[0][0] = fmaf(a0.x, w4.x, acc[0][0]);
      acc[0][1] = fmaf(a0.x, w4.y, acc[0][1]);
      acc[0][2] = fmaf(a0.x, w4.z, acc[0][2]);
      acc[0][3] = fmaf(a0.x, w4.w, acc[0][3]);
      acc[1][0] = fmaf(a0.y, w4.x, acc[1][0]);
      acc[1][1] = fmaf(a0.y, w4.y, acc[1][1]);
      acc[1][2] = fmaf(a0.y, w4.z, acc[1][2]);
      acc[1][3] = fmaf(a0.y, w4.w, acc[1][3]);
      acc[2][0] = fmaf(a0.z, w4.x, acc[2][0]);
      acc[2][1] = fmaf(a0.z, w4.y, acc[2][1]);
      acc[2][2] = fmaf(a0.z, w4.z, acc[2][2]);
      acc[2][3] = fmaf(a0.z, w4.w, acc[2][3]);
      acc[3][0] = fmaf(a0.w, w4.x, acc[3][0]);
      acc[3][1] = fmaf(a0.w, w4.y, acc[3][1]);
      acc[3][2] = fmaf(a0.w, w4.z, acc[3][2]);
      acc[3][3] = fmaf(a0.w, w4.w, acc[3][3]);
      acc[4][0] = fmaf(a1.x, w4.x, acc[4][0]);
      acc[4][1] = fmaf(a1.x, w4.y, acc[4][1]);
      acc[4][2] = fmaf(a1.x, w4.z, acc[4][2]);
      acc[4][3] = fmaf(a1.x, w4.w, acc[4][3]);
      acc[5][0] = fmaf(a1.y, w4.x, acc[5][0]);
      acc[5][1] = fmaf(a1.y, w4.y, acc[5][1]);
      acc[5][2] = fmaf(a1.y, w4.z, acc[5][2]);
      acc[5][3] = fmaf(a1.y, w4.w, acc[5][3]);
      acc[6][0] = fmaf(a1.z, w4.x, acc[6][0]);
      acc[6][1] = fmaf(a1.z, w4.y, acc[6][1]);
      acc[6][2] = fmaf(a1.z, w4.z, acc[6][2]);
      acc[6][3] = fmaf(a1.z, w4.w, acc[6][3]);
      acc[7][0] = fmaf(a1.w, w4.x, acc[7][0]);
      acc[7][1] = fmaf(a1.w, w4.y, acc[7][1]);
      acc[7][2] = fmaf(a1.w, w4.z, acc[7][2]);
      acc[7][3] = fmaf(a1.w, w4.w, acc[7][3]);
    }
    __syncthreads();
  }
  int o0 = og << 2;
  const float4 bv = *reinterpret_cast<const float4*>(&bias[o0]);
#pragma unroll
  for (int i = 0; i < 8; ++i) {
    int r = row0 + (rg << 3) + i;
    if (r < nNodes) {
      float4 res = make_float4(acc[i][0] + bv.x, acc[i][1] + bv.y,
                               acc[i][2] + bv.z, acc[i][3] + bv.w);
      *reinterpret_cast<float4*>(out + (((long long)r) << 7) + o0) = res;
    }
  }
}

extern "C" void kernel_launch(void* const* d_in, const int* in_sizes, int n_in,
                              void* d_out, int out_size, void* d_ws,
                              size_t ws_size, hipStream_t stream) {
  const float* x = (const float*)d_in[0];
  const int* rows = (const int*)d_in[1];
  const int* cols = (const int*)d_in[2];
  const float* vals = (const float*)d_in[3];
  const float* W = (const float*)d_in[4];
  const float* b = (const float*)d_in[5];
  float* out = (float*)d_out;

  int nEdges = in_sizes[1];
  int nNodes = in_sizes[0] / CH;
  int nPrjBlocks = (nNodes + PRJ_ROWS - 1) / PRJ_ROWS;
  int NB = (nNodes + SCAN_CHUNK - 1) / SCAN_CHUNK;

  // ws layout (ints): rowPtr[N+1] | cnt[N] | cursor[N] | bsum[256] | boff[256]
  //                   | (pad to 8B) | ecv[2E]
  size_t head = (size_t)(3 * nNodes + 1 + 512);
  size_t ecvOff = (head + 1) & ~(size_t)1;  // 8B align
  size_t needBytes = (ecvOff + 2 * (size_t)nEdges) * 4;

  if (ws_size < needBytes || NB > 256) {
    hipLaunchKernelGGL(k_init, dim3(2048), dim3(256), 0, stream, (float4*)out,
                       out_size / 4);
    hipLaunchKernelGGL(k_scatter, dim3(4096), dim3(256), 0, stream, x, rows,
                       cols, vals, out, nEdges);
    hipLaunchKernelGGL(k_project, dim3(nPrjBlocks), dim3(256), 0, stream, out,
                       W, b, nNodes);
    return;
  }

  int* wsI = (int*)d_ws;
  int* rowPtr = wsI;
  int* cnt = rowPtr + (nNodes + 1);
  int* cursor = cnt + nNodes;
  int* bsum = cursor + nNodes;
  int* boff = bsum + 256;
  int2* ecv = (int2*)(wsI + ecvOff);

  hipMemsetAsync(cnt, 0, (size_t)nNodes * 4, stream);
  hipLaunchKernelGGL(k_hist, dim3(2048), dim3(256), 0, stream, rows, cnt,
                     nEdges);
  hipLaunchKernelGGL(k_scan1, dim3(NB), dim3(256), 0, stream, cnt, rowPtr,
                     bsum, nNodes);
  hipLaunchKernelGGL(k_scan2, dim3(1), dim3(256), 0, stream, bsum, boff,
                     rowPtr + nNodes, NB);
  hipLaunchKernelGGL(k_scan3, dim3(NB), dim3(256), 0, stream, rowPtr, cursor,
                     boff, nNodes);
  hipLaunchKernelGGL(k_fill, dim3(2048), dim3(256), 0, stream, rows, cols,
                     vals, cursor, ecv, nEdges);
  hipLaunchKernelGGL(k_aggregate, dim3((nNodes + 3) / 4), dim3(256), 0, stream,
                     x, rowPtr, ecv, out, nNodes);
  hipLaunchKernelGGL(k_project, dim3(nPrjBlocks), dim3(256), 0, stream, out, W,
                     b, nNodes);
}